// Round 4
// baseline (851.648 us; speedup 1.0000x reference)
//
#include <hip/hip_runtime.h>
#include <hip/hip_cooperative_groups.h>

namespace cg = cooperative_groups;

#define D_FEAT 128
#define BLK 256

__global__ void __launch_bounds__(BLK, 4) fused_gcn_kernel(
    const float* __restrict__ x, const int* __restrict__ h, const int* __restrict__ t,
    float* __restrict__ out, int* __restrict__ counts, int* __restrict__ row_ptr,
    int* __restrict__ cursor, float* __restrict__ dis, int* __restrict__ bsum,
    int* __restrict__ edge_src, int N, int E)
{
    cg::grid_group grid = cg::this_grid();
    int* hcnt = counts;
    int* tcnt = counts + N;

    const int tid  = threadIdx.x;
    const int gid  = blockIdx.x * BLK + tid;
    const int nth  = gridDim.x * BLK;
    const int lane = tid & 63;
    const int wid  = tid >> 6;

    __shared__ int wsum[4];
    __shared__ int wpre[4];
    __shared__ int blk_prefix;

    // ---- P0: zero counters ----
    for (int i = gid; i < 2 * N; i += nth) counts[i] = 0;
    grid.sync();

    // ---- P1: histograms (deg of h for norm; count of t for CSR) ----
    for (int i = gid; i < E; i += nth) {
        atomicAdd(&hcnt[h[i]], 1);
        atomicAdd(&tcnt[t[i]], 1);
    }
    grid.sync();

    // ---- P2a: per-thread chunk sum + block scan of tcnt ----
    const int IT = (N + nth - 1) / nth;     // elements per thread (1 normally)
    const long long base_i = (long long)gid * IT;
    int v = 0;
    for (int k = 0; k < IT; ++k) {
        long long i = base_i + k;
        if (i < N) v += tcnt[i];
    }
    // wave-inclusive scan of per-thread sums
    int s = v;
    #pragma unroll
    for (int off = 1; off < 64; off <<= 1) {
        int u = __shfl_up(s, off, 64);
        if (lane >= off) s += u;
    }
    if (lane == 63) wsum[wid] = s;
    __syncthreads();
    if (tid == 0) {
        int run = 0;
        #pragma unroll
        for (int w2 = 0; w2 < 4; ++w2) { wpre[w2] = run; run += wsum[w2]; }
        bsum[blockIdx.x] = run;             // block total
    }
    __syncthreads();
    const int excl_in_block = wpre[wid] + s - v;  // thread's exclusive base in block
    grid.sync();

    // ---- P2b: cross-block prefix; write row_ptr, cursor, dis ----
    int p = 0;
    for (int b = tid; b < (int)blockIdx.x; b += BLK) p += bsum[b];
    #pragma unroll
    for (int off = 32; off > 0; off >>= 1) p += __shfl_down(p, off, 64);
    if (lane == 0) wsum[wid] = p;           // reuse (barrier-separated)
    __syncthreads();
    if (tid == 0) blk_prefix = wsum[0] + wsum[1] + wsum[2] + wsum[3];
    __syncthreads();
    int run = excl_in_block + blk_prefix;
    for (int k = 0; k < IT; ++k) {
        long long i = base_i + k;
        if (i < N) {
            int c = tcnt[i];
            row_ptr[i] = run;
            cursor[i]  = run;
            dis[i]     = rsqrtf((float)hcnt[i]);
            run += c;
        }
    }
    if (gid == 0) row_ptr[N] = E;
    grid.sync();

    // ---- P3: place edges (counting-sort by target) ----
    for (int i = gid; i < E; i += nth) {
        int pos = atomicAdd(&cursor[t[i]], 1);
        edge_src[pos] = h[i];
    }
    grid.sync();

    // ---- P4: gather + ReLU. 32 lanes per node, predicated unroll-4 ----
    const float4* x4 = reinterpret_cast<const float4*>(x);
    const int j = tid & 31;
    const int groups = nth >> 5;
    for (int node = gid >> 5; node < N; node += groups) {
        int beg = row_ptr[node];
        int end = row_ptr[node + 1];
        float4 acc = make_float4(0.f, 0.f, 0.f, 0.f);
        for (int k = beg; k < end; k += 4) {
            #pragma unroll
            for (int u = 0; u < 4; ++u) {
                int kk = k + u;
                bool m = kk < end;
                int idx = m ? kk : (end - 1);
                int s2 = edge_src[idx];
                float nr = m ? dis[s2] : 0.f;
                float4 vv = x4[(size_t)s2 * 32 + j];
                acc.x = fmaf(nr, vv.x, acc.x);
                acc.y = fmaf(nr, vv.y, acc.y);
                acc.z = fmaf(nr, vv.z, acc.z);
                acc.w = fmaf(nr, vv.w, acc.w);
            }
        }
        float dd = dis[node];
        float4 r;
        r.x = fmaxf(dd * acc.x, 0.f);
        r.y = fmaxf(dd * acc.y, 0.f);
        r.z = fmaxf(dd * acc.z, 0.f);
        r.w = fmaxf(dd * acc.w, 0.f);
        reinterpret_cast<float4*>(out)[(size_t)node * 32 + j] = r;
    }
}

extern "C" void kernel_launch(void* const* d_in, const int* in_sizes, int n_in,
                              void* d_out, int out_size, void* d_ws, size_t ws_size,
                              hipStream_t stream) {
    const float* x = (const float*)d_in[0];
    const int*   h = (const int*)d_in[1];
    const int*   t = (const int*)d_in[2];
    float* out = (float*)d_out;

    int N = in_sizes[0] / D_FEAT;   // 100000
    int E = in_sizes[1];            // 600000

    char* w = (char*)d_ws;
    size_t off = 0;
    auto alloc = [&](size_t bytes) {
        char* p = w + off;
        off = (off + bytes + 255) & ~(size_t)255;
        return p;
    };
    int*   counts   = (int*)alloc((size_t)2 * N * 4);  // hcnt | tcnt
    int*   row_ptr  = (int*)alloc((size_t)(N + 1) * 4);
    int*   cursor   = (int*)alloc((size_t)N * 4);
    float* dis      = (float*)alloc((size_t)N * 4);
    int*   bsum     = (int*)alloc((size_t)4096 * 4);
    int*   edge_src = (int*)alloc((size_t)E * 4);

    // Size the cooperative grid (host-side queries; capture-safe).
    int maxb = 0;
    hipError_t err = hipOccupancyMaxActiveBlocksPerMultiprocessor(
        &maxb, (const void*)fused_gcn_kernel, BLK, 0);
    if (err != hipSuccess || maxb < 1) maxb = 2;
    if (maxb > 16) maxb = 16;
    int ncu = 256;
    hipDeviceProp_t prop;
    int dev = 0;
    if (hipGetDevice(&dev) == hipSuccess &&
        hipGetDeviceProperties(&prop, dev) == hipSuccess &&
        prop.multiProcessorCount > 0) {
        ncu = prop.multiProcessorCount;
    }
    int nblocks = maxb * ncu;
    if (nblocks > 4096) nblocks = 4096;

    void* args[] = { (void*)&x, (void*)&h, (void*)&t, (void*)&out,
                     (void*)&counts, (void*)&row_ptr, (void*)&cursor,
                     (void*)&dis, (void*)&bsum, (void*)&edge_src,
                     (void*)&N, (void*)&E };
    hipLaunchCooperativeKernel((const void*)fused_gcn_kernel,
                               dim3(nblocks), dim3(BLK), args, 0, stream);
}

// Round 5
// 137.274 us; speedup vs baseline: 6.2040x; 6.2040x over previous
//
#include <hip/hip_runtime.h>

#define D_FEAT 128
#define SCAN_BLK 1024

__device__ __forceinline__ unsigned short f2bf_rtn(float f) {
    unsigned int u = __float_as_uint(f);
    unsigned int r = (u + 0x7FFFu + ((u >> 16) & 1u)) >> 16;
    return (unsigned short)r;
}

// f32 -> bf16 copy of x (4 elems/thread, RTN).
__global__ void convert_kernel(const float* __restrict__ x, unsigned short* __restrict__ xb, int n4) {
    int i = blockIdx.x * blockDim.x + threadIdx.x;
    if (i < n4) {
        float4 v = reinterpret_cast<const float4*>(x)[i];
        ushort4 o;
        o.x = f2bf_rtn(v.x); o.y = f2bf_rtn(v.y);
        o.z = f2bf_rtn(v.z); o.w = f2bf_rtn(v.w);
        reinterpret_cast<ushort4*>(xb)[i] = o;
    }
}

// Histograms, 4 edges/thread via int4 loads.
__global__ void hist_kernel(const int* __restrict__ h, const int* __restrict__ t,
                            int* __restrict__ hcnt, int* __restrict__ tcnt, int E) {
    int i = blockIdx.x * blockDim.x + threadIdx.x;
    int E4 = E >> 2;
    if (i < E4) {
        int4 a = reinterpret_cast<const int4*>(h)[i];
        int4 b = reinterpret_cast<const int4*>(t)[i];
        atomicAdd(&hcnt[a.x], 1); atomicAdd(&hcnt[a.y], 1);
        atomicAdd(&hcnt[a.z], 1); atomicAdd(&hcnt[a.w], 1);
        atomicAdd(&tcnt[b.x], 1); atomicAdd(&tcnt[b.y], 1);
        atomicAdd(&tcnt[b.z], 1); atomicAdd(&tcnt[b.w], 1);
    }
    if (i == 0) {
        for (int k = E4 << 2; k < E; ++k) {
            atomicAdd(&hcnt[h[k]], 1);
            atomicAdd(&tcnt[t[k]], 1);
        }
    }
}

// Per-block exclusive scan: shuffle wave scan + LDS wave-sum scan.
__global__ void scan_block_kernel(const int* __restrict__ in, int* __restrict__ out,
                                  int* __restrict__ bsum, int n) {
    int i = blockIdx.x * SCAN_BLK + threadIdx.x;
    int v = (i < n) ? in[i] : 0;
    int lane = threadIdx.x & 63;
    int wid = threadIdx.x >> 6;
    int s = v;
    #pragma unroll
    for (int off = 1; off < 64; off <<= 1) {
        int u = __shfl_up(s, off, 64);
        if (lane >= off) s += u;
    }
    __shared__ int wsum[16];
    if (lane == 63) wsum[wid] = s;
    __syncthreads();
    if (threadIdx.x < 16) {
        int ws = wsum[threadIdx.x];
        #pragma unroll
        for (int off = 1; off < 16; off <<= 1) {
            int u = __shfl_up(ws, off, 16);
            if ((threadIdx.x & 15) >= off) ws += u;
        }
        wsum[threadIdx.x] = ws;
    }
    __syncthreads();
    int base = (wid > 0) ? wsum[wid - 1] : 0;
    int incl = base + s;
    if (i < n) out[i] = incl - v;
    if (threadIdx.x == SCAN_BLK - 1) bsum[blockIdx.x] = incl;
}

// Fused: add block-sum prefix, cursor copy, dis = deg^-1/2.
__global__ void finalize_kernel(int* __restrict__ row_ptr, const int* __restrict__ bsum,
                                int* __restrict__ cursor, const int* __restrict__ hcnt,
                                float* __restrict__ dis, int n, int E) {
    int chunk = blockIdx.x >> 2;   // 256-thread block -> its 1024-wide scan chunk
    int lane = threadIdx.x & 63;
    int wid = threadIdx.x >> 6;
    int v = (threadIdx.x < chunk) ? bsum[threadIdx.x] : 0;
    #pragma unroll
    for (int off = 32; off > 0; off >>= 1) v += __shfl_down(v, off, 64);
    __shared__ int ws[4];
    if (lane == 0) ws[wid] = v;
    __syncthreads();
    __shared__ int prefix;
    if (threadIdx.x == 0) prefix = ws[0] + ws[1] + ws[2] + ws[3];
    __syncthreads();
    int i = blockIdx.x * blockDim.x + threadIdx.x;
    if (i < n) {
        int r = row_ptr[i] + prefix;
        row_ptr[i] = r;
        cursor[i] = r;
        dis[i] = rsqrtf((float)hcnt[i]);
    }
    if (i == 0) row_ptr[n] = E;
}

// Bucket edges by target, 4 edges/thread via int4 loads.
__global__ void place_kernel(const int* __restrict__ h, const int* __restrict__ t,
                             int* __restrict__ cursor, int* __restrict__ edge_src, int E) {
    int i = blockIdx.x * blockDim.x + threadIdx.x;
    int E4 = E >> 2;
    if (i < E4) {
        int4 a = reinterpret_cast<const int4*>(h)[i];
        int4 b = reinterpret_cast<const int4*>(t)[i];
        edge_src[atomicAdd(&cursor[b.x], 1)] = a.x;
        edge_src[atomicAdd(&cursor[b.y], 1)] = a.y;
        edge_src[atomicAdd(&cursor[b.z], 1)] = a.z;
        edge_src[atomicAdd(&cursor[b.w], 1)] = a.w;
    }
    if (i == 0) {
        for (int k = E4 << 2; k < E; ++k)
            edge_src[atomicAdd(&cursor[t[k]], 1)] = h[k];
    }
}

// bf16 gather: 16 lanes/node, lane j owns feats [8j, 8j+8). One uint4 (16B) = 8 bf16
// per lane per edge -> full 256B row in one load instruction. Predicated unroll-4.
__global__ void gather_bf16_kernel(const unsigned int* __restrict__ xb,
                                   const int* __restrict__ row_ptr,
                                   const int* __restrict__ edge_src,
                                   const float* __restrict__ dis,
                                   float* __restrict__ out, int n) {
    int gid = blockIdx.x * blockDim.x + threadIdx.x;
    int node = gid >> 4;
    int j = gid & 15;
    if (node >= n) return;
    int beg = row_ptr[node];
    int end = row_ptr[node + 1];
    const uint4* x16 = reinterpret_cast<const uint4*>(xb);
    float a0 = 0.f, a1 = 0.f, a2 = 0.f, a3 = 0.f, a4 = 0.f, a5 = 0.f, a6 = 0.f, a7 = 0.f;
    for (int k = beg; k < end; k += 4) {
        #pragma unroll
        for (int u = 0; u < 4; ++u) {
            int kk = k + u;
            bool m = kk < end;
            int idx = m ? kk : (end - 1);
            int s = edge_src[idx];
            float nr = m ? dis[s] : 0.f;
            uint4 v = x16[(size_t)s * 16 + j];
            float f0 = __uint_as_float(v.x << 16);
            float f1 = __uint_as_float(v.x & 0xFFFF0000u);
            float f2 = __uint_as_float(v.y << 16);
            float f3 = __uint_as_float(v.y & 0xFFFF0000u);
            float f4 = __uint_as_float(v.z << 16);
            float f5 = __uint_as_float(v.z & 0xFFFF0000u);
            float f6 = __uint_as_float(v.w << 16);
            float f7 = __uint_as_float(v.w & 0xFFFF0000u);
            a0 = fmaf(nr, f0, a0); a1 = fmaf(nr, f1, a1);
            a2 = fmaf(nr, f2, a2); a3 = fmaf(nr, f3, a3);
            a4 = fmaf(nr, f4, a4); a5 = fmaf(nr, f5, a5);
            a6 = fmaf(nr, f6, a6); a7 = fmaf(nr, f7, a7);
        }
    }
    float dd = dis[node];
    float4 r0, r1;
    r0.x = fmaxf(dd * a0, 0.f); r0.y = fmaxf(dd * a1, 0.f);
    r0.z = fmaxf(dd * a2, 0.f); r0.w = fmaxf(dd * a3, 0.f);
    r1.x = fmaxf(dd * a4, 0.f); r1.y = fmaxf(dd * a5, 0.f);
    r1.z = fmaxf(dd * a6, 0.f); r1.w = fmaxf(dd * a7, 0.f);
    float4* o4 = reinterpret_cast<float4*>(out) + (size_t)node * 32 + j * 2;
    o4[0] = r0;
    o4[1] = r1;
}

// f32 fallback gather (32 lanes/node, predicated unroll-4), as in round 3.
__global__ void gather_f32_kernel(const float* __restrict__ x, const int* __restrict__ row_ptr,
                                  const int* __restrict__ edge_src, const float* __restrict__ dis,
                                  float* __restrict__ out, int n) {
    int gid = blockIdx.x * blockDim.x + threadIdx.x;
    int node = gid >> 5;
    int j = gid & 31;
    if (node >= n) return;
    int beg = row_ptr[node];
    int end = row_ptr[node + 1];
    const float4* x4 = reinterpret_cast<const float4*>(x);
    float4 acc = make_float4(0.f, 0.f, 0.f, 0.f);
    for (int k = beg; k < end; k += 4) {
        #pragma unroll
        for (int u = 0; u < 4; ++u) {
            int kk = k + u;
            bool m = kk < end;
            int idx = m ? kk : (end - 1);
            int s = edge_src[idx];
            float nr = m ? dis[s] : 0.f;
            float4 vv = x4[(size_t)s * 32 + j];
            acc.x = fmaf(nr, vv.x, acc.x);
            acc.y = fmaf(nr, vv.y, acc.y);
            acc.z = fmaf(nr, vv.z, acc.z);
            acc.w = fmaf(nr, vv.w, acc.w);
        }
    }
    float dd = dis[node];
    float4 r;
    r.x = fmaxf(dd * acc.x, 0.f);
    r.y = fmaxf(dd * acc.y, 0.f);
    r.z = fmaxf(dd * acc.z, 0.f);
    r.w = fmaxf(dd * acc.w, 0.f);
    reinterpret_cast<float4*>(out)[(size_t)node * 32 + j] = r;
}

extern "C" void kernel_launch(void* const* d_in, const int* in_sizes, int n_in,
                              void* d_out, int out_size, void* d_ws, size_t ws_size,
                              hipStream_t stream) {
    const float* x = (const float*)d_in[0];
    const int*   h = (const int*)d_in[1];
    const int*   t = (const int*)d_in[2];
    float* out = (float*)d_out;

    int N = in_sizes[0] / D_FEAT;   // 100000
    int E = in_sizes[1];            // 600000
    int nb = (N + SCAN_BLK - 1) / SCAN_BLK;  // 98

    char* w = (char*)d_ws;
    size_t off = 0;
    auto alloc = [&](size_t bytes) {
        char* p = w + off;
        off = (off + bytes + 255) & ~(size_t)255;
        return p;
    };
    int*   counts   = (int*)alloc((size_t)2 * N * 4);  // hcnt | tcnt
    int*   hcnt     = counts;
    int*   tcnt     = counts + N;
    int*   row_ptr  = (int*)alloc((size_t)(N + 1) * 4);
    int*   cursor   = (int*)alloc((size_t)N * 4);
    float* dis      = (float*)alloc((size_t)N * 4);
    int*   bsum     = (int*)alloc((size_t)nb * 4);
    int*   edge_src = (int*)alloc((size_t)E * 4);
    size_t off_base = off;
    unsigned short* xb = (unsigned short*)alloc((size_t)N * D_FEAT * 2);
    bool use_bf16 = (off <= ws_size);
    (void)off_base;

    hipMemsetAsync(counts, 0, (size_t)2 * N * 4, stream);

    if (use_bf16) {
        int n4 = (N * D_FEAT) / 4;
        convert_kernel<<<(n4 + 255) / 256, 256, 0, stream>>>(x, xb, n4);
    }

    int e4b = ((E >> 2) + 255) / 256;
    hist_kernel<<<e4b, 256, 0, stream>>>(h, t, hcnt, tcnt, E);
    scan_block_kernel<<<nb, SCAN_BLK, 0, stream>>>(tcnt, row_ptr, bsum, N);
    finalize_kernel<<<(N + 255) / 256, 256, 0, stream>>>(row_ptr, bsum, cursor, hcnt, dis, N, E);
    place_kernel<<<e4b, 256, 0, stream>>>(h, t, cursor, edge_src, E);

    if (use_bf16) {
        long long total = (long long)N * 16;
        gather_bf16_kernel<<<(int)((total + 255) / 256), 256, 0, stream>>>(
            (const unsigned int*)xb, row_ptr, edge_src, dis, out, N);
    } else {
        long long total = (long long)N * 32;
        gather_f32_kernel<<<(int)((total + 255) / 256), 256, 0, stream>>>(
            x, row_ptr, edge_src, dis, out, N);
    }
}

// Round 6
// 137.178 us; speedup vs baseline: 6.2084x; 1.0007x over previous
//
#include <hip/hip_runtime.h>

#define D_FEAT 128
#define SCAN_BLK 1024

__device__ __forceinline__ unsigned short f2bf_rtn(float f) {
    unsigned int u = __float_as_uint(f);
    unsigned int r = (u + 0x7FFFu + ((u >> 16) & 1u)) >> 16;
    return (unsigned short)r;
}

// One atomic per thread: [0,E) -> hcnt via h, [E,2E) -> tcnt via t.
__global__ void hist_kernel(const int* __restrict__ h, const int* __restrict__ t,
                            int* __restrict__ hcnt, int* __restrict__ tcnt, int E) {
    int i = blockIdx.x * blockDim.x + threadIdx.x;
    if (i < E) {
        atomicAdd(&hcnt[h[i]], 1);
    } else {
        i -= E;
        if (i < E) atomicAdd(&tcnt[t[i]], 1);
    }
}

// Per-block exclusive scan: shuffle wave scan + LDS wave-sum scan.
__global__ void scan_block_kernel(const int* __restrict__ in, int* __restrict__ out,
                                  int* __restrict__ bsum, int n) {
    int i = blockIdx.x * SCAN_BLK + threadIdx.x;
    int v = (i < n) ? in[i] : 0;
    int lane = threadIdx.x & 63;
    int wid = threadIdx.x >> 6;
    int s = v;
    #pragma unroll
    for (int off = 1; off < 64; off <<= 1) {
        int u = __shfl_up(s, off, 64);
        if (lane >= off) s += u;
    }
    __shared__ int wsum[16];
    if (lane == 63) wsum[wid] = s;
    __syncthreads();
    if (threadIdx.x < 16) {
        int ws = wsum[threadIdx.x];
        #pragma unroll
        for (int off = 1; off < 16; off <<= 1) {
            int u = __shfl_up(ws, off, 16);
            if ((threadIdx.x & 15) >= off) ws += u;
        }
        wsum[threadIdx.x] = ws;
    }
    __syncthreads();
    int base = (wid > 0) ? wsum[wid - 1] : 0;
    int incl = base + s;
    if (i < n) out[i] = incl - v;
    if (threadIdx.x == SCAN_BLK - 1) bsum[blockIdx.x] = incl;
}

// Fused: add block-sum prefix, cursor copy, dis = deg^-1/2.
__global__ void finalize_kernel(int* __restrict__ row_ptr, const int* __restrict__ bsum,
                                int* __restrict__ cursor, const int* __restrict__ hcnt,
                                float* __restrict__ dis, int n, int E) {
    int chunk = blockIdx.x >> 2;   // 256-thread block -> its 1024-wide scan chunk
    int lane = threadIdx.x & 63;
    int wid = threadIdx.x >> 6;
    int v = (threadIdx.x < chunk) ? bsum[threadIdx.x] : 0;
    #pragma unroll
    for (int off = 32; off > 0; off >>= 1) v += __shfl_down(v, off, 64);
    __shared__ int ws[4];
    if (lane == 0) ws[wid] = v;
    __syncthreads();
    __shared__ int prefix;
    if (threadIdx.x == 0) prefix = ws[0] + ws[1] + ws[2] + ws[3];
    __syncthreads();
    int i = blockIdx.x * blockDim.x + threadIdx.x;
    if (i < n) {
        int r = row_ptr[i] + prefix;
        row_ptr[i] = r;
        cursor[i] = r;
        dis[i] = rsqrtf((float)hcnt[i]);
    }
    if (i == 0) row_ptr[n] = E;
}

// Heterogeneous: threads [0,E) place edges (counting sort by target);
// threads [E, E+(N+1)*32) convert x -> bf16 pre-scaled by dis[row] (row N = zero row).
__global__ void place_convert_kernel(const int* __restrict__ h, const int* __restrict__ t,
                                     int* __restrict__ cursor, int* __restrict__ edge_src,
                                     const float* __restrict__ x, const float* __restrict__ dis,
                                     unsigned short* __restrict__ xb, int E, int N) {
    int gid = blockIdx.x * blockDim.x + threadIdx.x;
    if (gid < E) {
        int pos = atomicAdd(&cursor[t[gid]], 1);
        edge_src[pos] = h[gid];
        return;
    }
    int ci = gid - E;                       // 0 .. (N+1)*32
    int row = ci >> 5;                      // node id (row N = zero row)
    if (row > N) return;
    int c = ci & 31;                        // float4 chunk within row
    ushort4 o;
    if (row < N) {
        float4 v = reinterpret_cast<const float4*>(x)[(size_t)row * 32 + c];
        float sc = dis[row];
        o.x = f2bf_rtn(v.x * sc);
        o.y = f2bf_rtn(v.y * sc);
        o.z = f2bf_rtn(v.z * sc);
        o.w = f2bf_rtn(v.w * sc);
    } else {
        o.x = o.y = o.z = o.w = 0;
    }
    reinterpret_cast<ushort4*>(xb)[(size_t)row * 32 + c] = o;
}

// Plain place (f32 fallback path).
__global__ void place_kernel(const int* __restrict__ h, const int* __restrict__ t,
                             int* __restrict__ cursor, int* __restrict__ edge_src, int E) {
    int i = blockIdx.x * blockDim.x + threadIdx.x;
    if (i < E) {
        int pos = atomicAdd(&cursor[t[i]], 1);
        edge_src[pos] = h[i];
    }
}

// bf16 gather: 16 lanes/node, lane j owns feats [8j,8j+8). Rows pre-scaled by
// dis[src], so inner loop is load + 8 adds. Masked lanes read the zero row N.
__global__ void gather_bf16_kernel(const unsigned int* __restrict__ xb,
                                   const int* __restrict__ row_ptr,
                                   const int* __restrict__ edge_src,
                                   const float* __restrict__ dis,
                                   float* __restrict__ out, int n) {
    int gid = blockIdx.x * blockDim.x + threadIdx.x;
    int node = gid >> 4;
    int j = gid & 15;
    if (node >= n) return;
    int beg = row_ptr[node];
    int end = row_ptr[node + 1];
    const uint4* x16 = reinterpret_cast<const uint4*>(xb);
    float a0 = 0.f, a1 = 0.f, a2 = 0.f, a3 = 0.f, a4 = 0.f, a5 = 0.f, a6 = 0.f, a7 = 0.f;
    for (int k = beg; k < end; k += 4) {
        #pragma unroll
        for (int u = 0; u < 4; ++u) {
            int kk = k + u;
            bool m = kk < end;
            int s = m ? edge_src[kk] : n;   // edge_src padded +4; row n is zeros
            uint4 v = x16[(size_t)s * 16 + j];
            a0 += __uint_as_float(v.x << 16);
            a1 += __uint_as_float(v.x & 0xFFFF0000u);
            a2 += __uint_as_float(v.y << 16);
            a3 += __uint_as_float(v.y & 0xFFFF0000u);
            a4 += __uint_as_float(v.z << 16);
            a5 += __uint_as_float(v.z & 0xFFFF0000u);
            a6 += __uint_as_float(v.w << 16);
            a7 += __uint_as_float(v.w & 0xFFFF0000u);
        }
    }
    float dd = dis[node];
    float4 r0, r1;
    r0.x = fmaxf(dd * a0, 0.f); r0.y = fmaxf(dd * a1, 0.f);
    r0.z = fmaxf(dd * a2, 0.f); r0.w = fmaxf(dd * a3, 0.f);
    r1.x = fmaxf(dd * a4, 0.f); r1.y = fmaxf(dd * a5, 0.f);
    r1.z = fmaxf(dd * a6, 0.f); r1.w = fmaxf(dd * a7, 0.f);
    float4* o4 = reinterpret_cast<float4*>(out) + (size_t)node * 32 + j * 2;
    o4[0] = r0;
    o4[1] = r1;
}

// f32 fallback gather (32 lanes/node, predicated unroll-4).
__global__ void gather_f32_kernel(const float* __restrict__ x, const int* __restrict__ row_ptr,
                                  const int* __restrict__ edge_src, const float* __restrict__ dis,
                                  float* __restrict__ out, int n) {
    int gid = blockIdx.x * blockDim.x + threadIdx.x;
    int node = gid >> 5;
    int j = gid & 31;
    if (node >= n) return;
    int beg = row_ptr[node];
    int end = row_ptr[node + 1];
    const float4* x4 = reinterpret_cast<const float4*>(x);
    float4 acc = make_float4(0.f, 0.f, 0.f, 0.f);
    for (int k = beg; k < end; k += 4) {
        #pragma unroll
        for (int u = 0; u < 4; ++u) {
            int kk = k + u;
            bool m = kk < end;
            int idx = m ? kk : (end - 1);
            int s = edge_src[idx];
            float nr = m ? dis[s] : 0.f;
            float4 vv = x4[(size_t)s * 32 + j];
            acc.x = fmaf(nr, vv.x, acc.x);
            acc.y = fmaf(nr, vv.y, acc.y);
            acc.z = fmaf(nr, vv.z, acc.z);
            acc.w = fmaf(nr, vv.w, acc.w);
        }
    }
    float dd = dis[node];
    float4 r;
    r.x = fmaxf(dd * acc.x, 0.f);
    r.y = fmaxf(dd * acc.y, 0.f);
    r.z = fmaxf(dd * acc.z, 0.f);
    r.w = fmaxf(dd * acc.w, 0.f);
    reinterpret_cast<float4*>(out)[(size_t)node * 32 + j] = r;
}

extern "C" void kernel_launch(void* const* d_in, const int* in_sizes, int n_in,
                              void* d_out, int out_size, void* d_ws, size_t ws_size,
                              hipStream_t stream) {
    const float* x = (const float*)d_in[0];
    const int*   h = (const int*)d_in[1];
    const int*   t = (const int*)d_in[2];
    float* out = (float*)d_out;

    int N = in_sizes[0] / D_FEAT;   // 100000
    int E = in_sizes[1];            // 600000
    int nb = (N + SCAN_BLK - 1) / SCAN_BLK;  // 98

    char* w = (char*)d_ws;
    size_t off = 0;
    auto alloc = [&](size_t bytes) {
        char* p = w + off;
        off = (off + bytes + 255) & ~(size_t)255;
        return p;
    };
    int*   counts   = (int*)alloc((size_t)2 * N * 4);  // hcnt | tcnt
    int*   hcnt     = counts;
    int*   tcnt     = counts + N;
    int*   row_ptr  = (int*)alloc((size_t)(N + 1) * 4);
    int*   cursor   = (int*)alloc((size_t)N * 4);
    float* dis      = (float*)alloc((size_t)N * 4);
    int*   bsum     = (int*)alloc((size_t)nb * 4);
    int*   edge_src = (int*)alloc((size_t)(E + 4) * 4);        // +4 pad for unroll reads
    unsigned short* xb = (unsigned short*)alloc((size_t)(N + 1) * D_FEAT * 2);  // +1 zero row
    bool use_bf16 = (off <= ws_size);

    hipMemsetAsync(counts, 0, (size_t)2 * N * 4, stream);

    // 1) histograms: one atomic per thread, 2E threads
    long long ht = 2LL * E;
    hist_kernel<<<(int)((ht + 255) / 256), 256, 0, stream>>>(h, t, hcnt, tcnt, E);

    // 2) scan of tcnt -> row_ptr (exclusive)
    scan_block_kernel<<<nb, SCAN_BLK, 0, stream>>>(tcnt, row_ptr, bsum, N);

    // 3) finalize: cross-block prefix, cursor, dis
    finalize_kernel<<<(N + 255) / 256, 256, 0, stream>>>(row_ptr, bsum, cursor, hcnt, dis, N, E);

    if (use_bf16) {
        // 4) place + pre-scaled bf16 convert (fused, independent halves)
        long long total = (long long)E + (long long)(N + 1) * 32;
        place_convert_kernel<<<(int)((total + 255) / 256), 256, 0, stream>>>(
            h, t, cursor, edge_src, x, dis, xb, E, N);
        // 5) gather + ReLU
        long long gt = (long long)N * 16;
        gather_bf16_kernel<<<(int)((gt + 255) / 256), 256, 0, stream>>>(
            (const unsigned int*)xb, row_ptr, edge_src, dis, out, N);
    } else {
        place_kernel<<<(E + 255) / 256, 256, 0, stream>>>(h, t, cursor, edge_src, E);
        long long gt = (long long)N * 32;
        gather_f32_kernel<<<(int)((gt + 255) / 256), 256, 0, stream>>>(
            x, row_ptr, edge_src, dis, out, N);
    }
}

// Round 7
// 134.533 us; speedup vs baseline: 6.3304x; 1.0197x over previous
//
#include <hip/hip_runtime.h>

#define D_FEAT 128
#define SCAN_BLK 1024

__device__ __forceinline__ unsigned short f2bf_rtn(float f) {
    unsigned int u = __float_as_uint(f);
    unsigned int r = (u + 0x7FFFu + ((u >> 16) & 1u)) >> 16;
    return (unsigned short)r;
}

// K1: heterogeneous. Threads [0,E): hcnt atomic via h. [E,2E): tcnt atomic via t.
// [2E, 2E + nconv*32): unscaled f32->bf16 convert of x (row-chunk per thread).
// The convert is pure-BW work hidden under the ~49us atomic drain.
__global__ void hist_convert_kernel(const int* __restrict__ h, const int* __restrict__ t,
                                    int* __restrict__ hcnt, int* __restrict__ tcnt,
                                    const float* __restrict__ x, unsigned short* __restrict__ xb,
                                    int E, int nconv) {
    int gid = blockIdx.x * blockDim.x + threadIdx.x;
    if (gid < E) {
        atomicAdd(&hcnt[h[gid]], 1);
        return;
    }
    int i = gid - E;
    if (i < E) {
        atomicAdd(&tcnt[t[i]], 1);
        return;
    }
    int ci = i - E;                        // 0 .. nconv*32
    int row = ci >> 5;
    if (row >= nconv) return;
    int c = ci & 31;
    size_t idx = (size_t)row * 32 + c;
    float4 v = reinterpret_cast<const float4*>(x)[idx];
    ushort4 o;
    o.x = f2bf_rtn(v.x);
    o.y = f2bf_rtn(v.y);
    o.z = f2bf_rtn(v.z);
    o.w = f2bf_rtn(v.w);
    reinterpret_cast<ushort4*>(xb)[idx] = o;
}

// Per-block exclusive scan: shuffle wave scan + LDS wave-sum scan.
__global__ void scan_block_kernel(const int* __restrict__ in, int* __restrict__ out,
                                  int* __restrict__ bsum, int n) {
    int i = blockIdx.x * SCAN_BLK + threadIdx.x;
    int v = (i < n) ? in[i] : 0;
    int lane = threadIdx.x & 63;
    int wid = threadIdx.x >> 6;
    int s = v;
    #pragma unroll
    for (int off = 1; off < 64; off <<= 1) {
        int u = __shfl_up(s, off, 64);
        if (lane >= off) s += u;
    }
    __shared__ int wsum[16];
    if (lane == 63) wsum[wid] = s;
    __syncthreads();
    if (threadIdx.x < 16) {
        int ws = wsum[threadIdx.x];
        #pragma unroll
        for (int off = 1; off < 16; off <<= 1) {
            int u = __shfl_up(ws, off, 16);
            if ((threadIdx.x & 15) >= off) ws += u;
        }
        wsum[threadIdx.x] = ws;
    }
    __syncthreads();
    int base = (wid > 0) ? wsum[wid - 1] : 0;
    int incl = base + s;
    if (i < n) out[i] = incl - v;
    if (threadIdx.x == SCAN_BLK - 1) bsum[blockIdx.x] = incl;
}

// Fused: add block-sum prefix, cursor copy, dis = deg^-1/2.
__global__ void finalize_kernel(int* __restrict__ row_ptr, const int* __restrict__ bsum,
                                int* __restrict__ cursor, const int* __restrict__ hcnt,
                                float* __restrict__ dis, int n, int E) {
    int chunk = blockIdx.x >> 2;   // 256-thread block -> its 1024-wide scan chunk
    int lane = threadIdx.x & 63;
    int wid = threadIdx.x >> 6;
    int v = (threadIdx.x < chunk) ? bsum[threadIdx.x] : 0;
    #pragma unroll
    for (int off = 32; off > 0; off >>= 1) v += __shfl_down(v, off, 64);
    __shared__ int ws[4];
    if (lane == 0) ws[wid] = v;
    __syncthreads();
    __shared__ int prefix;
    if (threadIdx.x == 0) prefix = ws[0] + ws[1] + ws[2] + ws[3];
    __syncthreads();
    int i = blockIdx.x * blockDim.x + threadIdx.x;
    if (i < n) {
        int r = row_ptr[i] + prefix;
        row_ptr[i] = r;
        cursor[i] = r;
        dis[i] = rsqrtf((float)hcnt[i]);
    }
    if (i == 0) row_ptr[n] = E;
}

// Bucket edges by target: edge_src[pos] = h[e]. One edge per thread.
__global__ void place_kernel(const int* __restrict__ h, const int* __restrict__ t,
                             int* __restrict__ cursor, int* __restrict__ edge_src, int E) {
    int i = blockIdx.x * blockDim.x + threadIdx.x;
    if (i < E) {
        int pos = atomicAdd(&cursor[t[i]], 1);
        edge_src[pos] = h[i];
    }
}

// bf16 gather: 16 lanes/node, lane j owns feats [8j,8j+8). Per-edge norm dis[s].
__global__ void gather_bf16_kernel(const unsigned int* __restrict__ xb,
                                   const int* __restrict__ row_ptr,
                                   const int* __restrict__ edge_src,
                                   const float* __restrict__ dis,
                                   float* __restrict__ out, int n) {
    int gid = blockIdx.x * blockDim.x + threadIdx.x;
    int node = gid >> 4;
    int j = gid & 15;
    if (node >= n) return;
    int beg = row_ptr[node];
    int end = row_ptr[node + 1];
    const uint4* x16 = reinterpret_cast<const uint4*>(xb);
    float a0 = 0.f, a1 = 0.f, a2 = 0.f, a3 = 0.f, a4 = 0.f, a5 = 0.f, a6 = 0.f, a7 = 0.f;
    for (int k = beg; k < end; k += 4) {
        #pragma unroll
        for (int u = 0; u < 4; ++u) {
            int kk = k + u;
            bool m = kk < end;
            int idx = m ? kk : (end - 1);   // end > beg guaranteed inside loop
            int s = edge_src[idx];
            float nr = m ? dis[s] : 0.f;
            uint4 v = x16[(size_t)s * 16 + j];
            a0 = fmaf(nr, __uint_as_float(v.x << 16), a0);
            a1 = fmaf(nr, __uint_as_float(v.x & 0xFFFF0000u), a1);
            a2 = fmaf(nr, __uint_as_float(v.y << 16), a2);
            a3 = fmaf(nr, __uint_as_float(v.y & 0xFFFF0000u), a3);
            a4 = fmaf(nr, __uint_as_float(v.z << 16), a4);
            a5 = fmaf(nr, __uint_as_float(v.z & 0xFFFF0000u), a5);
            a6 = fmaf(nr, __uint_as_float(v.w << 16), a6);
            a7 = fmaf(nr, __uint_as_float(v.w & 0xFFFF0000u), a7);
        }
    }
    float dd = dis[node];
    float4 r0, r1;
    r0.x = fmaxf(dd * a0, 0.f); r0.y = fmaxf(dd * a1, 0.f);
    r0.z = fmaxf(dd * a2, 0.f); r0.w = fmaxf(dd * a3, 0.f);
    r1.x = fmaxf(dd * a4, 0.f); r1.y = fmaxf(dd * a5, 0.f);
    r1.z = fmaxf(dd * a6, 0.f); r1.w = fmaxf(dd * a7, 0.f);
    float4* o4 = reinterpret_cast<float4*>(out) + (size_t)node * 32 + j * 2;
    o4[0] = r0;
    o4[1] = r1;
}

// f32 fallback gather (32 lanes/node, predicated unroll-4).
__global__ void gather_f32_kernel(const float* __restrict__ x, const int* __restrict__ row_ptr,
                                  const int* __restrict__ edge_src, const float* __restrict__ dis,
                                  float* __restrict__ out, int n) {
    int gid = blockIdx.x * blockDim.x + threadIdx.x;
    int node = gid >> 5;
    int j = gid & 31;
    if (node >= n) return;
    int beg = row_ptr[node];
    int end = row_ptr[node + 1];
    const float4* x4 = reinterpret_cast<const float4*>(x);
    float4 acc = make_float4(0.f, 0.f, 0.f, 0.f);
    for (int k = beg; k < end; k += 4) {
        #pragma unroll
        for (int u = 0; u < 4; ++u) {
            int kk = k + u;
            bool m = kk < end;
            int idx = m ? kk : (end - 1);
            int s = edge_src[idx];
            float nr = m ? dis[s] : 0.f;
            float4 vv = x4[(size_t)s * 32 + j];
            acc.x = fmaf(nr, vv.x, acc.x);
            acc.y = fmaf(nr, vv.y, acc.y);
            acc.z = fmaf(nr, vv.z, acc.z);
            acc.w = fmaf(nr, vv.w, acc.w);
        }
    }
    float dd = dis[node];
    float4 r;
    r.x = fmaxf(dd * acc.x, 0.f);
    r.y = fmaxf(dd * acc.y, 0.f);
    r.z = fmaxf(dd * acc.z, 0.f);
    r.w = fmaxf(dd * acc.w, 0.f);
    reinterpret_cast<float4*>(out)[(size_t)node * 32 + j] = r;
}

extern "C" void kernel_launch(void* const* d_in, const int* in_sizes, int n_in,
                              void* d_out, int out_size, void* d_ws, size_t ws_size,
                              hipStream_t stream) {
    const float* x = (const float*)d_in[0];
    const int*   h = (const int*)d_in[1];
    const int*   t = (const int*)d_in[2];
    float* out = (float*)d_out;

    int N = in_sizes[0] / D_FEAT;   // 100000
    int E = in_sizes[1];            // 600000
    int nb = (N + SCAN_BLK - 1) / SCAN_BLK;  // 98

    char* w = (char*)d_ws;
    size_t off = 0;
    auto alloc = [&](size_t bytes) {
        char* p = w + off;
        off = (off + bytes + 255) & ~(size_t)255;
        return p;
    };
    int*   counts   = (int*)alloc((size_t)2 * N * 4);  // hcnt | tcnt
    int*   hcnt     = counts;
    int*   tcnt     = counts + N;
    int*   row_ptr  = (int*)alloc((size_t)(N + 1) * 4);
    int*   cursor   = (int*)alloc((size_t)N * 4);
    float* dis      = (float*)alloc((size_t)N * 4);
    int*   bsum     = (int*)alloc((size_t)nb * 4);
    int*   edge_src = (int*)alloc((size_t)E * 4);
    unsigned short* xb = (unsigned short*)alloc((size_t)N * D_FEAT * 2);
    bool use_bf16 = (off <= ws_size);

    hipMemsetAsync(counts, 0, (size_t)2 * N * 4, stream);

    // 1) K1: both histograms (atomic-rate-bound) + unscaled bf16 convert (BW, hidden)
    int nconv = use_bf16 ? N : 0;
    long long k1t = 2LL * E + (long long)nconv * 32;
    hist_convert_kernel<<<(int)((k1t + 255) / 256), 256, 0, stream>>>(
        h, t, hcnt, tcnt, x, xb, E, nconv);

    // 2) scan of tcnt -> row_ptr (exclusive)
    scan_block_kernel<<<nb, SCAN_BLK, 0, stream>>>(tcnt, row_ptr, bsum, N);

    // 3) finalize: cross-block prefix, cursor, dis
    finalize_kernel<<<(N + 255) / 256, 256, 0, stream>>>(row_ptr, bsum, cursor, hcnt, dis, N, E);

    // 4) place: counting-sort edges by target
    place_kernel<<<(E + 255) / 256, 256, 0, stream>>>(h, t, cursor, edge_src, E);

    // 5) gather + ReLU
    if (use_bf16) {
        long long gt = (long long)N * 16;
        gather_bf16_kernel<<<(int)((gt + 255) / 256), 256, 0, stream>>>(
            (const unsigned int*)xb, row_ptr, edge_src, dis, out, N);
    } else {
        long long gt = (long long)N * 32;
        gather_f32_kernel<<<(int)((gt + 255) / 256), 256, 0, stream>>>(
            x, row_ptr, edge_src, dis, out, N);
    }
}